// Round 3
// baseline (16.745 us; speedup 1.0000x reference)
//
#include <hip/hip_runtime.h>
#include <math.h>

// Problem constants (from setup_inputs): bs=2, Q=256, C=16, P=20, T=256
#define BS    2
#define NQ    256
#define NCLS  16
#define NP    20
#define NT    256
#define NN    (BS * NQ)    // 512 predictions
#define FEPS  1e-6f
#define QPL   5            // target points per lane (NP / 4)
#define TPB   64           // targets per block
#define THREADS 256

// Grid: NN * (NT/TPB) = 2048 blocks x 256 threads = 8192 waves (8 / SIMD).
// Each quad of lanes (tid&3) handles one target t; lane z owns target points
// q in [5z, 5z+5). m2 (gt->pred min) is complete per lane (all p seen);
// m1 (pred->gt min) combines across the quad with a 2-step shfl_xor butterfly.
// Softmax exps computed once per block into LDS.
__global__ __launch_bounds__(THREADS, 8) void matcher_cost_kernel(
    const float* __restrict__ logits,   // [NN, NCLS]
    const float* __restrict__ ppoly,    // [NN, NP, 2]
    const int*   __restrict__ tlabels,  // [NT]
    const float* __restrict__ tpoly,    // [NT, NP, 2]
    float*       __restrict__ out)      // [NN, NT]
{
    const int bid   = blockIdx.x;
    const int n     = bid >> 2;              // prediction index
    const int tbase = (bid & 3) * TPB;
    const int tid   = threadIdx.x;           // 0..255
    const int t     = tbase + (tid >> 2);    // target index
    const int z     = tid & 3;               // q-quarter

    __shared__ float s_px[NP], s_py[NP];
    __shared__ float s_logit[NCLS];
    __shared__ float s_prob[NCLS];           // exp(logit - max), shared

    // --- stage pred polyline + logits ---
    if (tid < NP * 2) {
        float v = ppoly[n * NP * 2 + tid];
        if (tid & 1) s_py[tid >> 1] = v;
        else         s_px[tid >> 1] = v;
    }
    if (tid < NCLS) s_logit[tid] = logits[n * NCLS + tid];
    __syncthreads();

    if (tid < NCLS) {
        float mx = s_logit[0];
        #pragma unroll
        for (int c = 1; c < NCLS; ++c) mx = fmaxf(mx, s_logit[c]);
        s_prob[tid] = __expf(s_logit[tid] - mx);
    }
    __syncthreads();

    // --- load this lane's 5 target points (blocked: q = 5z..5z+4) ---
    float tx[QPL], ty[QPL], m2[QPL];
    const float* tp = &tpoly[(t * NP + z * QPL) * 2];
    #pragma unroll
    for (int k = 0; k < QPL; ++k) {
        float2 v = *reinterpret_cast<const float2*>(&tp[2 * k]);
        tx[k] = v.x; ty[k] = v.y; m2[k] = 1e30f;
    }

    // --- polyline cost ---
    float sum1 = 0.f;
    #pragma unroll
    for (int p = 0; p < NP; ++p) {
        const float px = s_px[p];   // uniform LDS broadcast
        const float py = s_py[p];
        float d0 = fabsf(px - tx[0]) + fabsf(py - ty[0]);
        float d1 = fabsf(px - tx[1]) + fabsf(py - ty[1]);
        float d2 = fabsf(px - tx[2]) + fabsf(py - ty[2]);
        float d3 = fabsf(px - tx[3]) + fabsf(py - ty[3]);
        float d4 = fabsf(px - tx[4]) + fabsf(py - ty[4]);
        m2[0] = fminf(m2[0], d0);
        m2[1] = fminf(m2[1], d1);
        m2[2] = fminf(m2[2], d2);
        m2[3] = fminf(m2[3], d3);
        m2[4] = fminf(m2[4], d4);
        // tree min of this lane's 5, then quad butterfly
        float m1 = fminf(fminf(fminf(d0, d1), fminf(d2, d3)), d4);
        m1 = fminf(m1, __shfl_xor(m1, 1));
        m1 = fminf(m1, __shfl_xor(m1, 2));
        sum1 += m1;   // identical in all 4 lanes
    }
    float sum2 = ((m2[0] + m2[1]) + (m2[2] + m2[3])) + m2[4];
    sum2 += __shfl_xor(sum2, 1);
    sum2 += __shfl_xor(sum2, 2);

    const float cost_poly = (sum1 + sum2) * (0.5f / (float)NP);

    // --- classification cost: -prob[lbl] / sum(prob) ---
    float denom = 0.f;
    #pragma unroll
    for (int c = 0; c < NCLS; ++c) denom += s_prob[c];
    const int lbl = tlabels[t];
    const float cost_class = -s_prob[lbl] / denom;

    // --- direction cost: 1 - cos(start->end) ---
    float pdx = s_px[NP - 1] - s_px[0];
    float pdy = s_py[NP - 1] - s_py[0];
    const float pn = sqrtf(pdx * pdx + pdy * pdy) + FEPS;
    pdx /= pn; pdy /= pn;

    // this lane holds only 5 of 20 points; fetch endpoints directly (L1-hit)
    float2 g0 = *reinterpret_cast<const float2*>(&tpoly[t * NP * 2]);
    float2 g1 = *reinterpret_cast<const float2*>(&tpoly[(t * NP + NP - 1) * 2]);
    float gdx = g1.x - g0.x;
    float gdy = g1.y - g0.y;
    const float gn = sqrtf(gdx * gdx + gdy * gdy) + FEPS;
    gdx /= gn; gdy /= gn;

    const float cost_dir = 1.f - (pdx * gdx + pdy * gdy);

    if (z == 0) out[n * NT + t] = cost_class + cost_poly + cost_dir;
}

extern "C" void kernel_launch(void* const* d_in, const int* in_sizes, int n_in,
                              void* d_out, int out_size, void* d_ws, size_t ws_size,
                              hipStream_t stream) {
    const float* logits  = (const float*)d_in[0];  // [2,256,16]
    const float* ppoly   = (const float*)d_in[1];  // [2,256,20,2]
    const int*   tlabels = (const int*)d_in[2];    // [256]
    const float* tpoly   = (const float*)d_in[3];  // [256,20,2]
    float*       out     = (float*)d_out;          // [2,256,256]

    matcher_cost_kernel<<<dim3(NN * (NT / TPB)), dim3(THREADS), 0, stream>>>(
        logits, ppoly, tlabels, tpoly, out);
}

// Round 4
// 13.450 us; speedup vs baseline: 1.2450x; 1.2450x over previous
//
#include <hip/hip_runtime.h>
#include <math.h>

// Problem constants (from setup_inputs): bs=2, Q=256, C=16, P=20, T=256
#define BS    2
#define NQ    256
#define NCLS  16
#define NP    20
#define NT    256
#define NN    (BS * NQ)    // 512 predictions
#define FEPS  1e-6f
#define QPL   5            // target points per lane (NP / 4)
#define TPB   64           // targets per block
#define PHALF 10           // p-chunk per butterfly batch
#define THREADS 256

// Grid: NN * (NT/TPB) = 2048 blocks x 256 threads = 8192 waves (8 / SIMD).
// Quad of lanes handles one target t; lane z owns target points q in
// [5z, 5z+5). Inner p-loop is pure VALU (no cross-lane ops): per-p partial
// mins buffered in m1a[10] registers; quad butterflies done in bulk after
// each 10-p half (independent, pipelined, off the critical path).
// Per-block uniform work (softmax exps, denom, pred direction) done once by
// wave 0 between the two syncthreads.
__global__ __launch_bounds__(THREADS, 8) void matcher_cost_kernel(
    const float* __restrict__ logits,   // [NN, NCLS]
    const float* __restrict__ ppoly,    // [NN, NP, 2]
    const int*   __restrict__ tlabels,  // [NT]
    const float* __restrict__ tpoly,    // [NT, NP, 2]
    float*       __restrict__ out)      // [NN, NT]
{
    const int bid   = blockIdx.x;
    const int n     = bid >> 2;              // prediction index
    const int tbase = (bid & 3) * TPB;
    const int tid   = threadIdx.x;           // 0..255
    const int t     = tbase + (tid >> 2);    // target index
    const int z     = tid & 3;               // q-quarter

    __shared__ float2 s_pxy[NP];             // pred polyline, interleaved
    __shared__ float  s_logit[NCLS];
    __shared__ float  s_prob[NCLS];          // exp(logit - max)
    __shared__ float  s_dir[2];              // normalized pred direction
    __shared__ float  s_invden;              // 1 / sum(exp)

    // --- stage pred polyline + logits ---
    if (tid < NP * 2) ((float*)s_pxy)[tid] = ppoly[n * NP * 2 + tid];
    if (tid < NCLS)   s_logit[tid] = logits[n * NCLS + tid];
    __syncthreads();

    // --- wave-0 aux: softmax pieces + pred direction (uniform per block) ---
    if (tid < NCLS) {
        float mx = s_logit[0];
        #pragma unroll
        for (int c = 1; c < NCLS; ++c) mx = fmaxf(mx, s_logit[c]);
        s_prob[tid] = __expf(s_logit[tid] - mx);
    }
    if (tid == 0) {   // same wave as the writers above: program order is enough
        float den = 0.f;
        #pragma unroll
        for (int c = 0; c < NCLS; ++c) den += s_prob[c];
        s_invden = 1.f / den;
    }
    if (tid == 16) {
        float2 a = s_pxy[0], b = s_pxy[NP - 1];
        float dx = b.x - a.x, dy = b.y - a.y;
        float nrm = sqrtf(dx * dx + dy * dy) + FEPS;
        s_dir[0] = dx / nrm; s_dir[1] = dy / nrm;
    }

    // --- load this lane's 5 target points ---
    float tx[QPL], ty[QPL], m2[QPL];
    const float* tp = &tpoly[(t * NP + z * QPL) * 2];
    #pragma unroll
    for (int k = 0; k < QPL; ++k) {
        float2 v = *reinterpret_cast<const float2*>(&tp[2 * k]);
        tx[k] = v.x; ty[k] = v.y; m2[k] = 1e30f;
    }

    // --- polyline cost: pure-VALU inner loop, bulk butterflies per half ---
    float sum1 = 0.f;
    float m1a[PHALF];
    #pragma unroll
    for (int h = 0; h < 2; ++h) {
        #pragma unroll
        for (int pp = 0; pp < PHALF; ++pp) {
            const float2 pxy = s_pxy[h * PHALF + pp];   // uniform broadcast
            const float d0 = fabsf(pxy.x - tx[0]) + fabsf(pxy.y - ty[0]);
            const float d1 = fabsf(pxy.x - tx[1]) + fabsf(pxy.y - ty[1]);
            const float d2 = fabsf(pxy.x - tx[2]) + fabsf(pxy.y - ty[2]);
            const float d3 = fabsf(pxy.x - tx[3]) + fabsf(pxy.y - ty[3]);
            const float d4 = fabsf(pxy.x - tx[4]) + fabsf(pxy.y - ty[4]);
            m2[0] = fminf(m2[0], d0);
            m2[1] = fminf(m2[1], d1);
            m2[2] = fminf(m2[2], d2);
            m2[3] = fminf(m2[3], d3);
            m2[4] = fminf(m2[4], d4);
            m1a[pp] = fminf(fminf(fminf(d0, d1), d2), fminf(d3, d4));
        }
        // bulk quad-butterfly: 10 independent chains, pipelined
        float s = 0.f;
        #pragma unroll
        for (int pp = 0; pp < PHALF; ++pp) {
            float v = m1a[pp];
            v = fminf(v, __shfl_xor(v, 1));
            v = fminf(v, __shfl_xor(v, 2));
            s += v;
        }
        sum1 += s;
    }
    float sum2 = ((m2[0] + m2[1]) + (m2[2] + m2[3])) + m2[4];
    sum2 += __shfl_xor(sum2, 1);
    sum2 += __shfl_xor(sum2, 2);
    const float cost_poly = (sum1 + sum2) * (0.5f / (float)NP);

    // --- target endpoints via quad shfl (lane 0 has q=0, lane 3 has q=19) ---
    const float g0x = __shfl(tx[0], 0, 4);
    const float g0y = __shfl(ty[0], 0, 4);
    const float g1x = __shfl(tx[QPL - 1], 3, 4);
    const float g1y = __shfl(ty[QPL - 1], 3, 4);

    __syncthreads();   // s_prob / s_invden / s_dir ready

    if (z == 0) {
        const int lbl = tlabels[t];
        const float cost_class = -s_prob[lbl] * s_invden;

        const float gdx = g1x - g0x, gdy = g1y - g0y;
        const float gn = sqrtf(gdx * gdx + gdy * gdy) + FEPS;
        const float cost_dir = 1.f - (s_dir[0] * gdx + s_dir[1] * gdy) / gn;

        out[n * NT + t] = cost_class + cost_poly + cost_dir;
    }
}

extern "C" void kernel_launch(void* const* d_in, const int* in_sizes, int n_in,
                              void* d_out, int out_size, void* d_ws, size_t ws_size,
                              hipStream_t stream) {
    const float* logits  = (const float*)d_in[0];  // [2,256,16]
    const float* ppoly   = (const float*)d_in[1];  // [2,256,20,2]
    const int*   tlabels = (const int*)d_in[2];    // [256]
    const float* tpoly   = (const float*)d_in[3];  // [256,20,2]
    float*       out     = (float*)d_out;          // [2,256,256]

    matcher_cost_kernel<<<dim3(NN * (NT / TPB)), dim3(THREADS), 0, stream>>>(
        logits, ppoly, tlabels, tpoly, out);
}